// Round 1
// baseline (192.931 us; speedup 1.0000x reference)
//
#include <hip/hip_runtime.h>
#include <math.h>

#define D 64
#define S 4

// ---------------- workspace layout (float offsets) ----------------
// [0,256)    keys[S][D]
// [256,260)  st_norm[S]        (normalized softplus strengths)
// [260,264)  uw_sums[S]        (atomic accumulators, zeroed each launch)
// [264,268)  last_writer[S]    (int, init -1 each launch)
// [272,336)  out1[D]           (272*4=1088 bytes, 16B aligned)
#define WS_KEYS 0
#define WS_ST   256
#define WS_SUMS 260
#define WS_LW   264
#define WS_OUT1 272

__global__ void k_prep(const float* __restrict__ slots,
                       const float* __restrict__ ss,
                       const float* __restrict__ Wk,
                       const float* __restrict__ bk,
                       float* __restrict__ ws) {
  int d = threadIdx.x;  // 64 threads
  __shared__ float sl[S][D];
  for (int s = 0; s < S; ++s) sl[s][d] = slots[s * D + d];
  __syncthreads();
  float bkd = bk[d];
  for (int s = 0; s < S; ++s) {
    float acc = bkd;
    for (int k = 0; k < D; ++k) acc = fmaf(sl[s][k], Wk[d * D + k], acc);
    ws[WS_KEYS + s * D + d] = tanhf(acc);
  }
  if (d < S) {
    ws[WS_SUMS + d] = 0.f;
    ((int*)ws)[WS_LW + d] = -1;
  }
  if (d == 0) {
    float st[S]; float tot = 0.f;
    for (int s = 0; s < S; ++s) {
      float x = ss[s];
      float sp = log1pf(expf(-fabsf(x))) + fmaxf(x, 0.f);  // softplus
      st[s] = sp; tot += sp;
    }
    for (int s = 0; s < S; ++s) ws[WS_ST + s] = st[s] / tot;
  }
}

__launch_bounds__(256)
__global__ void k_main(const float* __restrict__ item,
                       const float* __restrict__ Wq,
                       const float* __restrict__ bq,
                       float* ws,
                       float* __restrict__ slot_weights,
                       float* __restrict__ selected,
                       int B) {
  __shared__ float Wt[D][D];      // Wt[k][d] = Wq[d][k]
  __shared__ float keyss[S][D];
  __shared__ float sts[S];
  __shared__ float bqs[D];
  __shared__ float red_sum[4][S];
  __shared__ int   red_lw[4][S];

  int t = threadIdx.x;
  for (int i = t; i < D * D; i += 256) {
    int dd = i >> 6, kk = i & 63;
    Wt[kk][dd] = Wq[i];
  }
  for (int i = t; i < S * D; i += 256) keyss[i >> 6][i & 63] = ws[WS_KEYS + i];
  if (t < D) bqs[t] = bq[t];
  if (t >= D && t < D + S) sts[t - D] = ws[WS_ST + (t - D)];
  __syncthreads();

  int b = blockIdx.x * 256 + t;
  bool active = (b < B);

  float acc[D];
  #pragma unroll
  for (int d = 0; d < D; ++d) acc[d] = bqs[d];

  if (active) {
    const float4* row = (const float4*)(item + (size_t)b * D);
    for (int kk = 0; kk < 16; ++kk) {
      float4 iv = row[kk];
      #pragma unroll
      for (int j = 0; j < 4; ++j) {
        float x = (j == 0) ? iv.x : (j == 1) ? iv.y : (j == 2) ? iv.z : iv.w;
        int k = kk * 4 + j;
        #pragma unroll
        for (int d = 0; d < D; d += 4) {
          float4 wv = *(const float4*)&Wt[k][d];
          acc[d + 0] = fmaf(x, wv.x, acc[d + 0]);
          acc[d + 1] = fmaf(x, wv.y, acc[d + 1]);
          acc[d + 2] = fmaf(x, wv.z, acc[d + 2]);
          acc[d + 3] = fmaf(x, wv.w, acc[d + 3]);
        }
      }
    }
  }

  float uw0 = 0.f, uw1 = 0.f, uw2 = 0.f, uw3 = 0.f;
  int sel = 0;
  if (active) {
    for (int d = 0; d < D; ++d) acc[d] = tanhf(acc[d]);

    float sim[S];
    #pragma unroll
    for (int s = 0; s < S; ++s) {
      float a = 0.f;
      for (int d = 0; d < D; ++d) a = fmaf(acc[d], keyss[s][d], a);
      sim[s] = a;
    }

    float m = fmaxf(fmaxf(sim[0], sim[1]), fmaxf(sim[2], sim[3]));
    float e0 = expf(sim[0] - m), e1 = expf(sim[1] - m);
    float e2 = expf(sim[2] - m), e3 = expf(sim[3] - m);
    float se = e0 + e1 + e2 + e3;
    float w0 = e0 / se, w1 = e1 / se, w2 = e2 / se, w3 = e3 / se;

    float4 wout = make_float4(w0, w1, w2, w3);
    *(float4*)(slot_weights + (size_t)b * S) = wout;

    uw0 = w0 * sts[0]; uw1 = w1 * sts[1]; uw2 = w2 * sts[2]; uw3 = w3 * sts[3];
    float us = uw0 + uw1 + uw2 + uw3;
    uw0 /= us; uw1 /= us; uw2 /= us; uw3 /= us;

    float best = uw0;                 // first-max argmax (strict >)
    if (uw1 > best) { best = uw1; sel = 1; }
    if (uw2 > best) { best = uw2; sel = 2; }
    if (uw3 > best) { best = uw3; sel = 3; }

    selected[b] = (float)sel;
  }

  // ---- block reduction: uw sums (add) and last-writer (max) ----
  float r0 = uw0, r1 = uw1, r2 = uw2, r3 = uw3;
  int l0 = (active && sel == 0) ? b : -1;
  int l1 = (active && sel == 1) ? b : -1;
  int l2 = (active && sel == 2) ? b : -1;
  int l3 = (active && sel == 3) ? b : -1;
  #pragma unroll
  for (int off = 32; off > 0; off >>= 1) {
    r0 += __shfl_down(r0, off); r1 += __shfl_down(r1, off);
    r2 += __shfl_down(r2, off); r3 += __shfl_down(r3, off);
    int m0 = __shfl_down(l0, off); l0 = l0 > m0 ? l0 : m0;
    int m1 = __shfl_down(l1, off); l1 = l1 > m1 ? l1 : m1;
    int m2 = __shfl_down(l2, off); l2 = l2 > m2 ? l2 : m2;
    int m3 = __shfl_down(l3, off); l3 = l3 > m3 ? l3 : m3;
  }
  int lane = t & 63, wid = t >> 6;
  if (lane == 0) {
    red_sum[wid][0] = r0; red_sum[wid][1] = r1;
    red_sum[wid][2] = r2; red_sum[wid][3] = r3;
    red_lw[wid][0] = l0; red_lw[wid][1] = l1;
    red_lw[wid][2] = l2; red_lw[wid][3] = l3;
  }
  __syncthreads();
  if (t < S) {
    float tot = red_sum[0][t] + red_sum[1][t] + red_sum[2][t] + red_sum[3][t];
    atomicAdd(&ws[WS_SUMS + t], tot);
    int lm = red_lw[0][t];
    if (red_lw[1][t] > lm) lm = red_lw[1][t];
    if (red_lw[2][t] > lm) lm = red_lw[2][t];
    if (red_lw[3][t] > lm) lm = red_lw[3][t];
    atomicMax((int*)ws + WS_LW + t, lm);
  }
}

__global__ void k_final(const float* __restrict__ item,
                        const float* __restrict__ slots,
                        const float* __restrict__ usage,
                        const float* __restrict__ Wv,
                        const float* __restrict__ bv,
                        float* ws,
                        float* __restrict__ out_ns,
                        float* __restrict__ out_nu,
                        int B) {
  int d = threadIdx.x;  // 64 threads
  __shared__ float mean[D];
  const int* lw = (const int*)ws + WS_LW;
  float nsv[S];
  for (int s = 0; s < S; ++s) {
    int w = lw[s];
    float v = (w >= 0) ? item[(size_t)w * D + d] : slots[s * D + d];
    nsv[s] = v;
    out_ns[s * D + d] = v;
  }
  mean[d] = (nsv[0] + nsv[1] + nsv[2] + nsv[3]) * 0.25f;
  __syncthreads();
  float acc = bv[d];
  for (int k = 0; k < D; ++k) acc = fmaf(mean[k], Wv[d * D + k], acc);
  ws[WS_OUT1 + d] = tanhf(acc);
  if (d < S) out_nu[d] = usage[d] * 0.9f + ws[WS_SUMS + d] / (float)B;
}

__global__ void k_bcast(const float* __restrict__ ws,
                        float4* __restrict__ out, long n4) {
  __shared__ float4 o4[16];
  if (threadIdx.x < 16) o4[threadIdx.x] = ((const float4*)(ws + WS_OUT1))[threadIdx.x];
  __syncthreads();
  long i = (long)blockIdx.x * blockDim.x + threadIdx.x;
  long stride = (long)gridDim.x * blockDim.x;
  for (; i < n4; i += stride) out[i] = o4[i & 15];
}

extern "C" void kernel_launch(void* const* d_in, const int* in_sizes, int n_in,
                              void* d_out, int out_size, void* d_ws, size_t ws_size,
                              hipStream_t stream) {
  const float* item  = (const float*)d_in[0];
  const float* slots = (const float*)d_in[1];
  const float* ss    = (const float*)d_in[2];
  const float* usage = (const float*)d_in[3];
  const float* Wq    = (const float*)d_in[4];
  const float* bq    = (const float*)d_in[5];
  const float* Wk    = (const float*)d_in[6];
  const float* bk    = (const float*)d_in[7];
  const float* Wv    = (const float*)d_in[8];
  const float* bv    = (const float*)d_in[9];
  int B = in_sizes[0] / D;
  float* ws = (float*)d_ws;

  float* out_output       = (float*)d_out;
  float* out_new_slots    = out_output + (size_t)B * D;
  float* out_new_usage    = out_new_slots + S * D;
  float* out_selected     = out_new_usage + S;
  float* out_slot_weights = out_selected + B;

  k_prep<<<1, 64, 0, stream>>>(slots, ss, Wk, bk, ws);
  k_main<<<(B + 255) / 256, 256, 0, stream>>>(item, Wq, bq, ws,
                                              out_slot_weights, out_selected, B);
  k_final<<<1, 64, 0, stream>>>(item, slots, usage, Wv, bv, ws,
                                out_new_slots, out_new_usage, B);
  long n4 = (long)B * D / 4;
  k_bcast<<<2048, 256, 0, stream>>>(ws, (float4*)out_output, n4);
}